// Round 3
// baseline (1197.986 us; speedup 1.0000x reference)
//
#include <hip/hip_runtime.h>
#include <hip/hip_bf16.h>

constexpr int N_NODES = 100000;
constexpr int N_EDGES = 1600000;
constexpr int D = 64;
constexpr int NPB = 128;                          // nodes per bucket
constexpr int NBUK = (N_NODES + NPB - 1) / NPB;   // 782 buckets
constexpr int CAP = 4096;                         // slots/bucket (mean 2046, huge headroom)

// ---------------------------------------------------------------------------
// Phase 1: partition edges into dst-buckets as packed u32:
//   (dst & 127) << 17 | src          (src < 2^17)
// Active write frontier = 782 cache lines -> L2-coalesced writes.
// ---------------------------------------------------------------------------
__global__ void partition_kernel(const int* __restrict__ src,
                                 const int* __restrict__ dst,
                                 int* __restrict__ bcur,
                                 unsigned int* __restrict__ packed) {
    for (int e = blockIdx.x * blockDim.x + threadIdx.x; e < N_EDGES;
         e += gridDim.x * blockDim.x) {
        const int s = src[e];
        const int d = dst[e];
        const int buk = d >> 7;
        const int pos = atomicAdd(&bcur[buk], 1);
        if (pos < CAP)
            packed[((size_t)buk << 12) | pos] =
                ((unsigned)(d & (NPB - 1)) << 17) | (unsigned)s;
    }
}

// ---------------------------------------------------------------------------
// Phase 2: one block per bucket. LDS-accumulate h[128][64] via ds_add_f32,
// then per-lane matvec (W row j in 16 float4 regs) + bias + relu.
// 16-lane groups: group g = j>>4 handles edge i+g, lane covers float4 col j&15.
// ---------------------------------------------------------------------------
__global__ void fused_kernel(const float* __restrict__ feat,
                             const int* __restrict__ bcur,
                             const unsigned int* __restrict__ packed,
                             const float* __restrict__ W,
                             const float* __restrict__ bias,
                             float* __restrict__ out) {
    __shared__ float h[NPB * D];                  // 32 KiB

    const int tid = threadIdx.x;                  // 512 threads = 8 waves
    const int w   = tid >> 6;
    const int j   = tid & 63;
    const int g   = j >> 4;                       // edge group 0..3
    const int c4  = (j & 15) << 2;                // float4 column offset

    for (int i = tid; i < NPB * D; i += 512) h[i] = 0.0f;
    __syncthreads();

    const int buk = blockIdx.x;
    int cnt_all = bcur[buk];
    if (cnt_all > CAP) cnt_all = CAP;
    const unsigned int* bp = packed + ((size_t)buk << 12);

    // ---- edge accumulation: wave w takes 64-edge chunks w, w+8, ... ----
    for (int base = w * 64; base < cnt_all; base += 512) {
        int cnt = cnt_all - base; if (cnt > 64) cnt = 64;
        const unsigned pk = (j < cnt) ? bp[base + j] : 0u;

        int i = 0;
        for (; i + 16 <= cnt; i += 16) {          // 16 edges per super-iter
            const unsigned p0 = __shfl(pk, i + g);
            const unsigned p1 = __shfl(pk, i + 4 + g);
            const unsigned p2 = __shfl(pk, i + 8 + g);
            const unsigned p3 = __shfl(pk, i + 12 + g);
            const float4 v0 = *reinterpret_cast<const float4*>(feat + (size_t)(p0 & 0x1FFFFu) * D + c4);
            const float4 v1 = *reinterpret_cast<const float4*>(feat + (size_t)(p1 & 0x1FFFFu) * D + c4);
            const float4 v2 = *reinterpret_cast<const float4*>(feat + (size_t)(p2 & 0x1FFFFu) * D + c4);
            const float4 v3 = *reinterpret_cast<const float4*>(feat + (size_t)(p3 & 0x1FFFFu) * D + c4);
            float* h0 = &h[((p0 >> 17) << 6) + c4];
            float* h1 = &h[((p1 >> 17) << 6) + c4];
            float* h2 = &h[((p2 >> 17) << 6) + c4];
            float* h3 = &h[((p3 >> 17) << 6) + c4];
            atomicAdd(h0 + 0, v0.x); atomicAdd(h0 + 1, v0.y); atomicAdd(h0 + 2, v0.z); atomicAdd(h0 + 3, v0.w);
            atomicAdd(h1 + 0, v1.x); atomicAdd(h1 + 1, v1.y); atomicAdd(h1 + 2, v1.z); atomicAdd(h1 + 3, v1.w);
            atomicAdd(h2 + 0, v2.x); atomicAdd(h2 + 1, v2.y); atomicAdd(h2 + 2, v2.z); atomicAdd(h2 + 3, v2.w);
            atomicAdd(h3 + 0, v3.x); atomicAdd(h3 + 1, v3.y); atomicAdd(h3 + 2, v3.z); atomicAdd(h3 + 3, v3.w);
        }
        for (; i + 4 <= cnt; i += 4) {            // 4 edges per iter
            const unsigned p0 = __shfl(pk, i + g);
            const float4 v0 = *reinterpret_cast<const float4*>(feat + (size_t)(p0 & 0x1FFFFu) * D + c4);
            float* h0 = &h[((p0 >> 17) << 6) + c4];
            atomicAdd(h0 + 0, v0.x); atomicAdd(h0 + 1, v0.y); atomicAdd(h0 + 2, v0.z); atomicAdd(h0 + 3, v0.w);
        }
        if (i < cnt) {                            // tail: predicated per group
            const int ei = i + g;
            const unsigned p0 = __shfl(pk, (ei < cnt) ? ei : 0);
            if (ei < cnt) {
                const float4 v0 = *reinterpret_cast<const float4*>(feat + (size_t)(p0 & 0x1FFFFu) * D + c4);
                float* h0 = &h[((p0 >> 17) << 6) + c4];
                atomicAdd(h0 + 0, v0.x); atomicAdd(h0 + 1, v0.y); atomicAdd(h0 + 2, v0.z); atomicAdd(h0 + 3, v0.w);
            }
        }
    }
    __syncthreads();
    __builtin_amdgcn_sched_barrier(0);            // keep W loads in MLP phase

    // ---- MLP: W row j -> 16 float4 regs; h rows broadcast from LDS ----
    float4 wr[16];
    #pragma unroll
    for (int q = 0; q < 16; ++q)
        wr[q] = *reinterpret_cast<const float4*>(W + j * D + (q << 2));
    const float bj = bias[j];

    const int gbase = buk * NPB;
    for (int n = w; n < NPB; n += 8) {
        const int gn = gbase + n;
        if (gn >= N_NODES) break;
        const float* hr = &h[n << 6];
        float acc = bj;
        #pragma unroll
        for (int q = 0; q < 16; ++q) {
            const float4 hv = *reinterpret_cast<const float4*>(hr + (q << 2));   // broadcast
            acc = fmaf(hv.x, wr[q].x, acc);
            acc = fmaf(hv.y, wr[q].y, acc);
            acc = fmaf(hv.z, wr[q].z, acc);
            acc = fmaf(hv.w, wr[q].w, acc);
        }
        out[(size_t)gn * D + j] = fmaxf(acc, 0.0f);
    }
}

extern "C" void kernel_launch(void* const* d_in, const int* in_sizes, int n_in,
                              void* d_out, int out_size, void* d_ws, size_t ws_size,
                              hipStream_t stream) {
    const float* feat = (const float*)d_in[0];
    const int*   src  = (const int*)d_in[1];
    const int*   dst  = (const int*)d_in[2];
    const float* W    = (const float*)d_in[3];
    const float* b    = (const float*)d_in[4];
    float* out = (float*)d_out;

    int* bcur = (int*)d_ws;                                    // NBUK ints
    unsigned int* packed = (unsigned int*)((char*)d_ws + 4096); // NBUK*CAP u32 = 12.8 MB

    hipMemsetAsync(bcur, 0, NBUK * sizeof(int), stream);

    partition_kernel<<<2048, 256, 0, stream>>>(src, dst, bcur, packed);

    fused_kernel<<<NBUK, 512, 0, stream>>>(feat, bcur, packed, W, b, out);
}

// Round 4
// 193.448 us; speedup vs baseline: 6.1928x; 6.1928x over previous
//
#include <hip/hip_runtime.h>
#include <hip/hip_bf16.h>

constexpr int N_NODES = 100000;
constexpr int N_EDGES = 1600000;
constexpr int D = 64;
constexpr int NPB = 128;                          // nodes per bucket
constexpr int NBUK = (N_NODES + NPB - 1) / NPB;   // 782 buckets
constexpr int CAP = 4096;                         // slots per bucket (mean 2046, max ~2300)
constexpr int PART_BLOCKS = 64;
constexpr int EPB = (N_EDGES + PART_BLOCKS - 1) / PART_BLOCKS;  // 25000 edges/block

// ---------------------------------------------------------------------------
// Phase 1: privatized partition. Each block: LDS histogram over 782 buckets,
// one global atomicAdd per (block,bucket) to reserve a contiguous chunk, then
// contiguous chunk writes of packed (dlocal<<17 | src).
// ---------------------------------------------------------------------------
__global__ __launch_bounds__(256) void partition_kernel(
    const int* __restrict__ src, const int* __restrict__ dst,
    int* __restrict__ gtot, unsigned* __restrict__ packed) {
    __shared__ int lcnt[NBUK];    // histogram, then local cursor
    __shared__ int lbase[NBUK];   // reserved chunk base within bucket

    const int tid = threadIdx.x;
    const int lo = blockIdx.x * EPB;
    int hi = lo + EPB; if (hi > N_EDGES) hi = N_EDGES;

    for (int i = tid; i < NBUK; i += 256) lcnt[i] = 0;
    __syncthreads();

    for (int e = lo + tid; e < hi; e += 256)
        atomicAdd(&lcnt[dst[e] >> 7], 1);
    __syncthreads();

    for (int i = tid; i < NBUK; i += 256) {
        const int c = lcnt[i];
        lbase[i] = c ? atomicAdd(&gtot[i], c) : 0;
        lcnt[i] = 0;                               // reuse as local cursor
    }
    __syncthreads();

    for (int e = lo + tid; e < hi; e += 256) {
        const int d = dst[e];
        const int buk = d >> 7;
        const int p = lbase[buk] + atomicAdd(&lcnt[buk], 1);
        if (p < CAP)
            packed[((size_t)buk << 12) + p] =
                ((unsigned)(d & (NPB - 1)) << 17) | (unsigned)src[e];
    }
}

// ---------------------------------------------------------------------------
// Phase 2: one 512-thread block per bucket.
//   a) LDS count-sort of the bucket's edges into per-node lists (elist)
//   b) per-node gather (round-2 proven inner loop) + W-in-regs matvec + relu
// launch_bounds(512,1): keep wr[16] in VGPRs — NO scratch spill.
// ---------------------------------------------------------------------------
__global__ __launch_bounds__(512, 1) void bucket_kernel(
    const float* __restrict__ feat, const int* __restrict__ gtot,
    const unsigned* __restrict__ packed, const float* __restrict__ W,
    const float* __restrict__ bias, float* __restrict__ out) {
    __shared__ unsigned elist[CAP];   // 16 KiB: src ids sorted by local dst
    __shared__ int cnt[NPB];
    __shared__ int cur[NPB];
    __shared__ int inc[NPB];          // inclusive scan
    __shared__ float hrow[8][D];      // per-wave h staging

    const int tid = threadIdx.x;
    const int w = tid >> 6;
    const int j = tid & 63;
    const int buk = blockIdx.x;

    int m = gtot[buk]; if (m > CAP) m = CAP;
    const unsigned* bp = packed + ((size_t)buk << 12);

    if (tid < NPB) cnt[tid] = 0;
    __syncthreads();

    // a1) count
    for (int i = tid; i < m; i += 512)
        atomicAdd(&cnt[bp[i] >> 17], 1);
    __syncthreads();

    // a2) Hillis-Steele inclusive scan of cnt -> inc; cur = exclusive
    int x = 0;
    if (tid < NPB) { x = cnt[tid]; inc[tid] = x; }
    __syncthreads();
    for (int o = 1; o < NPB; o <<= 1) {
        int y = 0;
        if (tid < NPB && tid >= o) y = inc[tid - o];
        __syncthreads();
        if (tid < NPB) inc[tid] += y;
        __syncthreads();
    }
    if (tid < NPB) cur[tid] = inc[tid] - x;
    __syncthreads();

    // a3) scatter src ids into elist (LDS only)
    for (int i = tid; i < m; i += 512) {
        const unsigned pk = bp[i];
        const int p = atomicAdd(&cur[pk >> 17], 1);
        elist[p] = pk & 0x1FFFFu;
    }
    __syncthreads();

    // b) W row j -> 16 float4 regs (no spill thanks to launch_bounds)
    float4 wr[16];
    #pragma unroll
    for (int q = 0; q < 16; ++q)
        wr[q] = *reinterpret_cast<const float4*>(W + j * D + (q << 2));
    const float bj = bias[j];

    const int gbase = buk * NPB;
    for (int n = w; n < NPB; n += 8) {              // wave-private nodes, no barrier
        const int gn = gbase + n;
        if (gn >= N_NODES) break;
        const int e1 = inc[n];
        const int e0 = e1 - cnt[n];

        float h = 0.0f;
        int i = e0;
        for (; i + 8 <= e1; i += 8) {               // 8 gathers in flight
            const int s0 = elist[i + 0], s1 = elist[i + 1];
            const int s2 = elist[i + 2], s3 = elist[i + 3];
            const int s4 = elist[i + 4], s5 = elist[i + 5];
            const int s6 = elist[i + 6], s7 = elist[i + 7];
            const float v0 = feat[(size_t)s0 * D + j];
            const float v1 = feat[(size_t)s1 * D + j];
            const float v2 = feat[(size_t)s2 * D + j];
            const float v3 = feat[(size_t)s3 * D + j];
            const float v4 = feat[(size_t)s4 * D + j];
            const float v5 = feat[(size_t)s5 * D + j];
            const float v6 = feat[(size_t)s6 * D + j];
            const float v7 = feat[(size_t)s7 * D + j];
            h += v0 + v1 + v2 + v3 + v4 + v5 + v6 + v7;
        }
        for (; i < e1; ++i)
            h += feat[(size_t)elist[i] * D + j];

        hrow[w][j] = h;                              // wave-local, lockstep-safe
        float acc = bj;
        #pragma unroll
        for (int q = 0; q < 16; ++q) {
            const float4 hv = *reinterpret_cast<const float4*>(&hrow[w][q << 2]);
            acc = fmaf(hv.x, wr[q].x, acc);
            acc = fmaf(hv.y, wr[q].y, acc);
            acc = fmaf(hv.z, wr[q].z, acc);
            acc = fmaf(hv.w, wr[q].w, acc);
        }
        out[(size_t)gn * D + j] = fmaxf(acc, 0.0f);
    }
}

extern "C" void kernel_launch(void* const* d_in, const int* in_sizes, int n_in,
                              void* d_out, int out_size, void* d_ws, size_t ws_size,
                              hipStream_t stream) {
    const float* feat = (const float*)d_in[0];
    const int*   src  = (const int*)d_in[1];
    const int*   dst  = (const int*)d_in[2];
    const float* W    = (const float*)d_in[3];
    const float* b    = (const float*)d_in[4];
    float* out = (float*)d_out;

    int* gtot = (int*)d_ws;                                      // NBUK ints
    unsigned* packed = (unsigned*)((char*)d_ws + 4096);          // NBUK*CAP u32 = 12.8 MB

    hipMemsetAsync(gtot, 0, NBUK * sizeof(int), stream);

    partition_kernel<<<PART_BLOCKS, 256, 0, stream>>>(src, dst, gtot, packed);

    bucket_kernel<<<NBUK, 512, 0, stream>>>(feat, gtot, packed, W, b, out);
}

// Round 5
// 130.248 us; speedup vs baseline: 9.1977x; 1.4852x over previous
//
#include <hip/hip_runtime.h>
#include <hip/hip_bf16.h>

constexpr int N_NODES = 100000;
constexpr int N_EDGES = 1600000;
constexpr int D = 64;
constexpr int NPB = 64;                           // nodes per bucket
constexpr int NBUK = (N_NODES + NPB - 1) / NPB;   // 1563 buckets
constexpr int CAP = 2048;                         // slots/bucket (mean 1024, max ~1150)
constexpr int PART_BLOCKS = 64;
constexpr int PART_THREADS = 1024;
constexpr int EPB = (N_EDGES + PART_BLOCKS - 1) / PART_BLOCKS;  // 25000 edges/block

// ---------------------------------------------------------------------------
// Phase 1: privatized partition. Per block: LDS histogram over 1563 buckets,
// one global atomicAdd per (block,bucket) reserves a contiguous chunk, then
// chunk writes of packed (dlocal<<17 | src).  16 waves/block for latency.
// ---------------------------------------------------------------------------
__global__ __launch_bounds__(PART_THREADS) void partition_kernel(
    const int* __restrict__ src, const int* __restrict__ dst,
    int* __restrict__ gtot, unsigned* __restrict__ packed) {
    __shared__ int lcnt[NBUK];    // histogram, then local cursor
    __shared__ int lbase[NBUK];   // reserved chunk base within bucket

    const int tid = threadIdx.x;
    const int lo = blockIdx.x * EPB;
    int hi = lo + EPB; if (hi > N_EDGES) hi = N_EDGES;

    for (int i = tid; i < NBUK; i += PART_THREADS) lcnt[i] = 0;
    __syncthreads();

    #pragma unroll 4
    for (int e = lo + tid; e < hi; e += PART_THREADS)
        atomicAdd(&lcnt[dst[e] >> 6], 1);
    __syncthreads();

    for (int i = tid; i < NBUK; i += PART_THREADS) {
        const int c = lcnt[i];
        lbase[i] = c ? atomicAdd(&gtot[i], c) : 0;
        lcnt[i] = 0;                               // reuse as local cursor
    }
    __syncthreads();

    #pragma unroll 4
    for (int e = lo + tid; e < hi; e += PART_THREADS) {
        const int d = dst[e];
        const int buk = d >> 6;
        const int p = lbase[buk] + atomicAdd(&lcnt[buk], 1);
        if (p < CAP)
            packed[((size_t)buk << 11) + p] =
                ((unsigned)(d & (NPB - 1)) << 17) | (unsigned)src[e];
    }
}

// ---------------------------------------------------------------------------
// Phase 2: one 256-thread block per bucket (64 nodes).
//   a) LDS count-sort into per-node lists (single-wave shfl scan, 64 ctrs)
//   b) per-node gather with 16/8/4/1 ILP ladder + W-in-regs matvec + relu
// ---------------------------------------------------------------------------
__global__ __launch_bounds__(256, 4) void bucket_kernel(
    const float* __restrict__ feat, const int* __restrict__ gtot,
    const unsigned* __restrict__ packed, const float* __restrict__ W,
    const float* __restrict__ bias, float* __restrict__ out) {
    __shared__ unsigned elist[CAP];   // 8 KiB: src ids sorted by local dst
    __shared__ int cnt[NPB];
    __shared__ int cur[NPB];
    __shared__ int inc[NPB];
    __shared__ float hrow[4][D];

    const int tid = threadIdx.x;
    const int w = tid >> 6;
    const int j = tid & 63;
    const int buk = blockIdx.x;

    int m = gtot[buk]; if (m > CAP) m = CAP;
    const unsigned* bp = packed + ((size_t)buk << 11);

    if (tid < NPB) cnt[tid] = 0;
    __syncthreads();

    // a1) count
    #pragma unroll 4
    for (int i = tid; i < m; i += 256)
        atomicAdd(&cnt[bp[i] >> 17], 1);
    __syncthreads();

    // a2) single-wave inclusive shfl-scan over 64 counters
    if (tid < 64) {
        const int c = cnt[tid];
        int x = c;
        #pragma unroll
        for (int o = 1; o < 64; o <<= 1) {
            const int y = __shfl_up(x, o);
            if (tid >= o) x += y;
        }
        inc[tid] = x;
        cur[tid] = x - c;
    }
    __syncthreads();

    // a3) scatter src ids into elist (LDS only)
    #pragma unroll 4
    for (int i = tid; i < m; i += 256) {
        const unsigned pk = bp[i];
        const int p = atomicAdd(&cur[pk >> 17], 1);
        elist[p] = pk & 0x1FFFFu;
    }
    __syncthreads();

    // b) W row j -> 16 float4 regs
    float4 wr[16];
    #pragma unroll
    for (int q = 0; q < 16; ++q)
        wr[q] = *reinterpret_cast<const float4*>(W + j * D + (q << 2));
    const float bj = bias[j];

    const int gbase = buk * NPB;
    for (int n = w; n < NPB; n += 4) {              // wave-private nodes
        const int gn = gbase + n;
        if (gn >= N_NODES) break;
        const int e1 = inc[n];
        int i = e1 - cnt[n];

        float h = 0.0f;
        // 16-wide batch (wave-uniform branch, 16 loads in flight)
        for (; i + 16 <= e1; i += 16) {
            float v[16];
            #pragma unroll
            for (int k = 0; k < 16; ++k)
                v[k] = feat[(size_t)elist[i + k] * D + j];
            float s = 0.0f;
            #pragma unroll
            for (int k = 0; k < 16; ++k) s += v[k];
            h += s;
        }
        if (i + 8 <= e1) {
            float v[8];
            #pragma unroll
            for (int k = 0; k < 8; ++k)
                v[k] = feat[(size_t)elist[i + k] * D + j];
            #pragma unroll
            for (int k = 0; k < 8; ++k) h += v[k];
            i += 8;
        }
        if (i + 4 <= e1) {
            float v[4];
            #pragma unroll
            for (int k = 0; k < 4; ++k)
                v[k] = feat[(size_t)elist[i + k] * D + j];
            #pragma unroll
            for (int k = 0; k < 4; ++k) h += v[k];
            i += 4;
        }
        for (; i < e1; ++i)
            h += feat[(size_t)elist[i] * D + j];

        hrow[w][j] = h;                              // wave-local, lockstep-safe
        float acc = bj;
        #pragma unroll
        for (int q = 0; q < 16; ++q) {
            const float4 hv = *reinterpret_cast<const float4*>(&hrow[w][q << 2]);
            acc = fmaf(hv.x, wr[q].x, acc);
            acc = fmaf(hv.y, wr[q].y, acc);
            acc = fmaf(hv.z, wr[q].z, acc);
            acc = fmaf(hv.w, wr[q].w, acc);
        }
        out[(size_t)gn * D + j] = fmaxf(acc, 0.0f);
    }
}

extern "C" void kernel_launch(void* const* d_in, const int* in_sizes, int n_in,
                              void* d_out, int out_size, void* d_ws, size_t ws_size,
                              hipStream_t stream) {
    const float* feat = (const float*)d_in[0];
    const int*   src  = (const int*)d_in[1];
    const int*   dst  = (const int*)d_in[2];
    const float* W    = (const float*)d_in[3];
    const float* b    = (const float*)d_in[4];
    float* out = (float*)d_out;

    int* gtot = (int*)d_ws;                                      // NBUK ints (6.3 KB)
    unsigned* packed = (unsigned*)((char*)d_ws + 8192);          // NBUK*CAP u32 = 12.8 MB

    hipMemsetAsync(gtot, 0, NBUK * sizeof(int), stream);

    partition_kernel<<<PART_BLOCKS, PART_THREADS, 0, stream>>>(src, dst, gtot, packed);

    bucket_kernel<<<NBUK, 256, 0, stream>>>(feat, gtot, packed, W, b, out);
}

// Round 6
// 110.760 us; speedup vs baseline: 10.8160x; 1.1760x over previous
//
#include <hip/hip_runtime.h>
#include <hip/hip_bf16.h>

constexpr int N_NODES = 100000;
constexpr int N_EDGES = 1600000;
constexpr int D = 64;
constexpr int NPB = 64;                           // nodes per bucket
constexpr int NBUK = (N_NODES + NPB - 1) / NPB;   // 1563 buckets
constexpr int CAP = 2048;                         // slots/bucket (mean 1024, max ~1200)
constexpr int PART_BLOCKS = 256;
constexpr int PART_THREADS = 1024;
constexpr int EPB = (N_EDGES + PART_BLOCKS - 1) / PART_BLOCKS;  // 6250 edges/block

// ---------------------------------------------------------------------------
// Phase 1: privatized partition, all 256 CUs. Per block: LDS histogram over
// 1563 buckets, one global atomicAdd per (block,bucket) reserves a chunk,
// then chunk writes of packed (dlocal<<17 | src).
// ---------------------------------------------------------------------------
__global__ __launch_bounds__(PART_THREADS) void partition_kernel(
    const int* __restrict__ src, const int* __restrict__ dst,
    int* __restrict__ gtot, unsigned* __restrict__ packed) {
    __shared__ int lcnt[NBUK];    // histogram, then local cursor
    __shared__ int lbase[NBUK];   // reserved chunk base within bucket

    const int tid = threadIdx.x;
    const int lo = blockIdx.x * EPB;
    int hi = lo + EPB; if (hi > N_EDGES) hi = N_EDGES;

    for (int i = tid; i < NBUK; i += PART_THREADS) lcnt[i] = 0;
    __syncthreads();

    #pragma unroll 4
    for (int e = lo + tid; e < hi; e += PART_THREADS)
        atomicAdd(&lcnt[dst[e] >> 6], 1);
    __syncthreads();

    for (int i = tid; i < NBUK; i += PART_THREADS) {
        const int c = lcnt[i];
        lbase[i] = c ? atomicAdd(&gtot[i], c) : 0;
        lcnt[i] = 0;                               // reuse as local cursor
    }
    __syncthreads();

    #pragma unroll 4
    for (int e = lo + tid; e < hi; e += PART_THREADS) {
        const int d = dst[e];
        const int buk = d >> 6;
        const int p = lbase[buk] + atomicAdd(&lcnt[buk], 1);
        if (p < CAP)
            packed[((size_t)buk << 11) + p] =
                ((unsigned)(d & (NPB - 1)) << 17) | (unsigned)src[e];
    }
}

// ---------------------------------------------------------------------------
// Phase 2: one 256-thread block per bucket (64 nodes).
//   a) LDS count-sort into per-node lists (single-wave shfl scan)
//   b) float4 gather: 16-lane group g handles edge subsequence i+g+4k,
//      lane l covers columns 4l..4l+3 -> one dwordx4 per 4 edges.
//      Group-reduce via shfl_xor(16/32), then W-in-regs matvec + relu.
// ---------------------------------------------------------------------------
__global__ __launch_bounds__(256, 2) void bucket_kernel(
    const float* __restrict__ feat, const int* __restrict__ gtot,
    const unsigned* __restrict__ packed, const float* __restrict__ W,
    const float* __restrict__ bias, float* __restrict__ out) {
    __shared__ unsigned elist[CAP];   // 8 KiB: src ids sorted by local dst
    __shared__ int cnt[NPB];
    __shared__ int cur[NPB];
    __shared__ int inc[NPB];
    __shared__ float hrow[4][D];

    const int tid = threadIdx.x;
    const int w = tid >> 6;
    const int j = tid & 63;
    const int g = j >> 4;             // edge group 0..3
    const int l = j & 15;             // float4 column slot
    const int buk = blockIdx.x;

    // W row j -> 16 float4 regs, issued early so latency hides under sort
    float4 wr[16];
    #pragma unroll
    for (int q = 0; q < 16; ++q)
        wr[q] = *reinterpret_cast<const float4*>(W + j * D + (q << 2));
    const float bj = bias[j];

    int m = gtot[buk]; if (m > CAP) m = CAP;
    const unsigned* bp = packed + ((size_t)buk << 11);

    if (tid < NPB) cnt[tid] = 0;
    __syncthreads();

    // a1) count
    #pragma unroll 4
    for (int i = tid; i < m; i += 256)
        atomicAdd(&cnt[bp[i] >> 17], 1);
    __syncthreads();

    // a2) single-wave inclusive shfl-scan over 64 counters
    if (tid < 64) {
        const int c = cnt[tid];
        int x = c;
        #pragma unroll
        for (int o = 1; o < 64; o <<= 1) {
            const int y = __shfl_up(x, o);
            if (tid >= o) x += y;
        }
        inc[tid] = x;
        cur[tid] = x - c;
    }
    __syncthreads();

    // a3) scatter src ids into elist (LDS only)
    #pragma unroll 4
    for (int i = tid; i < m; i += 256) {
        const unsigned pk = bp[i];
        const int p = atomicAdd(&cur[pk >> 17], 1);
        elist[p] = pk & 0x1FFFFu;
    }
    __syncthreads();

    const float4* feat4 = reinterpret_cast<const float4*>(feat);
    const int gbase = buk * NPB;

    for (int n = w; n < NPB; n += 4) {              // wave-private nodes
        const int gn = gbase + n;
        if (gn >= N_NODES) break;
        const int e1 = inc[n];
        int i = e1 - cnt[n];

        float hx = 0.f, hy = 0.f, hz = 0.f, hw_ = 0.f;

        // 16 edges per iter: 4 dwordx4 in flight per lane
        for (; i + 16 <= e1; i += 16) {
            const int s0 = elist[i + g];            // 4-lane broadcast reads
            const int s1 = elist[i + 4 + g];
            const int s2 = elist[i + 8 + g];
            const int s3 = elist[i + 12 + g];
            const float4 v0 = feat4[(size_t)s0 * 16 + l];
            const float4 v1 = feat4[(size_t)s1 * 16 + l];
            const float4 v2 = feat4[(size_t)s2 * 16 + l];
            const float4 v3 = feat4[(size_t)s3 * 16 + l];
            hx += v0.x + v1.x + v2.x + v3.x;
            hy += v0.y + v1.y + v2.y + v3.y;
            hz += v0.z + v1.z + v2.z + v3.z;
            hw_ += v0.w + v1.w + v2.w + v3.w;
        }
        if (i + 8 <= e1) {
            const int s0 = elist[i + g];
            const int s1 = elist[i + 4 + g];
            const float4 v0 = feat4[(size_t)s0 * 16 + l];
            const float4 v1 = feat4[(size_t)s1 * 16 + l];
            hx += v0.x + v1.x; hy += v0.y + v1.y;
            hz += v0.z + v1.z; hw_ += v0.w + v1.w;
            i += 8;
        }
        if (i + 4 <= e1) {
            const float4 v0 = feat4[(size_t)elist[i + g] * 16 + l];
            hx += v0.x; hy += v0.y; hz += v0.z; hw_ += v0.w;
            i += 4;
        }
        const int rem = e1 - i;                     // 0..3 tail edges
        if (g < rem) {
            const float4 v0 = feat4[(size_t)elist[i + g] * 16 + l];
            hx += v0.x; hy += v0.y; hz += v0.z; hw_ += v0.w;
        }

        // reduce across the 4 edge groups (lanes l, l+16, l+32, l+48)
        hx += __shfl_xor(hx, 16); hx += __shfl_xor(hx, 32);
        hy += __shfl_xor(hy, 16); hy += __shfl_xor(hy, 32);
        hz += __shfl_xor(hz, 16); hz += __shfl_xor(hz, 32);
        hw_ += __shfl_xor(hw_, 16); hw_ += __shfl_xor(hw_, 32);

        if (g == 0)
            *reinterpret_cast<float4*>(&hrow[w][l << 2]) =
                make_float4(hx, hy, hz, hw_);       // lanes 0..15 cover all 64

        float acc = bj;
        #pragma unroll
        for (int q = 0; q < 16; ++q) {
            const float4 hv = *reinterpret_cast<const float4*>(&hrow[w][q << 2]);
            acc = fmaf(hv.x, wr[q].x, acc);
            acc = fmaf(hv.y, wr[q].y, acc);
            acc = fmaf(hv.z, wr[q].z, acc);
            acc = fmaf(hv.w, wr[q].w, acc);
        }
        out[(size_t)gn * D + j] = fmaxf(acc, 0.0f);
    }
}

extern "C" void kernel_launch(void* const* d_in, const int* in_sizes, int n_in,
                              void* d_out, int out_size, void* d_ws, size_t ws_size,
                              hipStream_t stream) {
    const float* feat = (const float*)d_in[0];
    const int*   src  = (const int*)d_in[1];
    const int*   dst  = (const int*)d_in[2];
    const float* W    = (const float*)d_in[3];
    const float* b    = (const float*)d_in[4];
    float* out = (float*)d_out;

    int* gtot = (int*)d_ws;                                      // NBUK ints (6.3 KB)
    unsigned* packed = (unsigned*)((char*)d_ws + 8192);          // NBUK*CAP u32 = 12.8 MB

    hipMemsetAsync(gtot, 0, NBUK * sizeof(int), stream);

    partition_kernel<<<PART_BLOCKS, PART_THREADS, 0, stream>>>(src, dst, gtot, packed);

    bucket_kernel<<<NBUK, 256, 0, stream>>>(feat, gtot, packed, W, b, out);
}